// Round 1
// 167.943 us; speedup vs baseline: 1.0046x; 1.0046x over previous
//
#include <hip/hip_runtime.h>
#include <limits.h>

// Fused: each block owns SPB consecutive segment ids. It scans the whole mask
// (128 KB, L2-resident) ONCE for both ids — halving the L2 re-read traffic vs
// one-seg-per-block — then gathers out[seg] = concat(x[first], x[last]) for
// both segments with exactly one float4 per thread.
constexpr int SPB = 2;  // segments per block

__global__ __launch_bounds__(1024) void fused_seg_gather(
    const int4* __restrict__ mask4, const float4* __restrict__ x,
    float4* __restrict__ out, int L4, int H4, int nseg) {
    const int seg0 = blockIdx.x * SPB;
    const int s0 = seg0, s1 = seg0 + 1;

    int fmin0 = INT_MAX, fmax0 = -1;
    int fmin1 = INT_MAX, fmax1 = -1;

    for (int k = threadIdx.x; k < L4; k += blockDim.x) {
        const int4 m = mask4[k];
        const int base = k << 2;
        if (m.x == s0) { fmin0 = min(fmin0, base);     fmax0 = max(fmax0, base);     }
        if (m.y == s0) { fmin0 = min(fmin0, base + 1); fmax0 = max(fmax0, base + 1); }
        if (m.z == s0) { fmin0 = min(fmin0, base + 2); fmax0 = max(fmax0, base + 2); }
        if (m.w == s0) { fmin0 = min(fmin0, base + 3); fmax0 = max(fmax0, base + 3); }
        if (m.x == s1) { fmin1 = min(fmin1, base);     fmax1 = max(fmax1, base);     }
        if (m.y == s1) { fmin1 = min(fmin1, base + 1); fmax1 = max(fmax1, base + 1); }
        if (m.z == s1) { fmin1 = min(fmin1, base + 2); fmax1 = max(fmax1, base + 2); }
        if (m.w == s1) { fmin1 = min(fmin1, base + 3); fmax1 = max(fmax1, base + 3); }
    }

    // wave (64-lane) shuffle reduction for both segments
    #pragma unroll
    for (int off = 32; off > 0; off >>= 1) {
        fmin0 = min(fmin0, __shfl_down(fmin0, off, 64));
        fmax0 = max(fmax0, __shfl_down(fmax0, off, 64));
        fmin1 = min(fmin1, __shfl_down(fmin1, off, 64));
        fmax1 = max(fmax1, __shfl_down(fmax1, off, 64));
    }

    __shared__ int s_min[16][SPB], s_max[16][SPB];
    const int wave = threadIdx.x >> 6;
    if ((threadIdx.x & 63) == 0) {
        s_min[wave][0] = fmin0; s_max[wave][0] = fmax0;
        s_min[wave][1] = fmin1; s_max[wave][1] = fmax1;
    }
    __syncthreads();
    const int nwaves = blockDim.x >> 6;
    if (threadIdx.x < SPB) {  // thread s reduces segment s across waves
        const int s = threadIdx.x;
        int mn = s_min[0][s], mx = s_max[0][s];
        for (int w = 1; w < nwaves; ++w) {
            mn = min(mn, s_min[w][s]);
            mx = max(mx, s_max[w][s]);
        }
        if (mx < 0) { mn = 0; mx = 0; }  // segment never occurs (not expected)
        s_min[0][s] = mn; s_max[0][s] = mx;
    }
    __syncthreads();

    // Gather: SPB segs × {first,last} × H4 float4 = 4*H4 = blockDim ops.
    const int total = SPB * 2 * H4;
    for (int t = threadIdx.x; t < total; t += blockDim.x) {
        const int col    = t % H4;
        const int which  = t / H4;   // 0: seg0.first, 1: seg0.last, 2: seg1.first, 3: seg1.last
        const int s      = which >> 1;
        const int isLast = which & 1;
        const int seg    = seg0 + s;
        if (seg >= nseg) continue;
        const int row = isLast ? s_max[0][s] : s_min[0][s];
        out[(size_t)seg * (size_t)(2 * H4) + (size_t)isLast * H4 + col] =
            x[(size_t)row * H4 + col];
    }
}

extern "C" void kernel_launch(void* const* d_in, const int* in_sizes, int n_in,
                              void* d_out, int out_size, void* d_ws, size_t ws_size,
                              hipStream_t stream) {
    const float* x  = (const float*)d_in[0];
    const int* mask = (const int*)d_in[1];   // number_mask (int32 on device)

    const int L = in_sizes[1];           // B*S = 32768
    const int H = in_sizes[0] / L;       // 1024
    const int n = out_size / (2 * H);    // 512 (concat == 1 per setup)

    const int L4 = L / 4;
    const int H4 = H / 4;

    const int grid = (n + SPB - 1) / SPB;   // 256 blocks, 2 segs each
    fused_seg_gather<<<grid, 1024, 0, stream>>>((const int4*)mask, (const float4*)x,
                                                (float4*)d_out, L4, H4, n);
}